// Round 4
// baseline (217.832 us; speedup 1.0000x reference)
//
#include <hip/hip_runtime.h>
#include <math.h>

#define B_ 256
#define G_ 4000
#define P_ 128
#define D_ 12000
#define H_ 64
#define O_ 16
#define GH_ 128
#define CH_ 8
#define C_ 5
#define K_ 3
#define EPS_ 1e-5f
#define KCH_ 500   // K-chunk per gemm1 block (4000/8)
#define KIN_ 100   // inner K tile staged in LDS
#define NCHK_ 8    // gene chunks per pathway (expert)
#define SG_ 32     // samples per group (expert)
#define GT_ 64     // gene subtile (expert)

// ---------------------------------------------------------------------------
// K1: fused preprocessing.
//   blocks [0,128):    per-pathway active-gene compaction (8 waves, 2-pass)
//   blocks [128,384):  gate GEMM1 partials over 8 k-chunks
// ---------------------------------------------------------------------------
__global__ __launch_bounds__(512) void k_pre(const float* __restrict__ gene_mask,
                                             const float* __restrict__ x_rna,
                                             const float* __restrict__ gw1,
                                             int* __restrict__ cnt,
                                             int* __restrict__ list,
                                             float* __restrict__ hpart) {
  int t = threadIdx.x;

  if (blockIdx.x < P_) {
    int p = blockIdx.x;
    int lane = t & 63;
    int w = t >> 6;
    __shared__ int wcnt[8];
    int* lp = list + (size_t)p * G_;
    const int per = (G_ + 7) / 8;   // 500
    int start = w * per;
    int end = start + per; if (end > G_) end = G_;

    int count = 0;
    for (int g0 = start; g0 < end; g0 += 64) {
      int g = g0 + lane;
      bool act = (g < end) && (gene_mask[(size_t)g * P_ + p] != 0.0f);
      count += __popcll(__ballot(act));
    }
    if (lane == 0) wcnt[w] = count;
    __syncthreads();
    if (t == 0) {
      int tot = 0;
      for (int i = 0; i < 8; ++i) tot += wcnt[i];
      cnt[p] = tot;
    }
    int base = 0;
    for (int i = 0; i < w; ++i) base += wcnt[i];
    for (int g0 = start; g0 < end; g0 += 64) {
      int g = g0 + lane;
      bool act = (g < end) && (gene_mask[(size_t)g * P_ + p] != 0.0f);
      unsigned long long bal = __ballot(act);
      int rank = __popcll(bal & ((1ull << lane) - 1ull));
      if (act) lp[base + rank] = g;
      base += __popcll(bal);
    }
    return;
  }

  // ---- gate GEMM1 partial tile ----
  int idx = blockIdx.x - P_;        // 0..255
  int bt = idx >> 5;                // 8 b-tiles of 32
  int sub = idx & 31;
  int jt = sub >> 3;                // 4 j-tiles of 32
  int kc = sub & 7;                 // 8 k-chunks of 500
  int b0 = bt * 32;
  int j0 = jt * 32;

  __shared__ float xa[32 * KIN_];
  __shared__ float wa[KIN_ * 32];
  float2* wa2 = (float2*)wa;

  int bi = t >> 4;
  int jp = t & 15;
  float2 acc = {0.f, 0.f};

  for (int ch = 0; ch < KCH_ / KIN_; ++ch) {
    int kb = kc * KCH_ + ch * KIN_;
    __syncthreads();
    for (int id = t; id < 32 * KIN_; id += 512) {
      int r = id / KIN_, c = id - r * KIN_;
      xa[id] = x_rna[(size_t)(b0 + r) * G_ + kb + c];
    }
    for (int id = t; id < KIN_ * 32; id += 512) {
      int r = id >> 5, c = id & 31;
      wa[id] = gw1[(size_t)(kb + r) * GH_ + j0 + c];
    }
    __syncthreads();
#pragma unroll 4
    for (int kk = 0; kk < KIN_; ++kk) {
      float a = xa[bi * KIN_ + kk];
      float2 w = wa2[kk * 16 + jp];
      acc.x = fmaf(a, w.x, acc.x);
      acc.y = fmaf(a, w.y, acc.y);
    }
  }
  float2* out = (float2*)(hpart + ((size_t)kc * B_ + (b0 + bi)) * GH_ + j0 + jp * 2);
  *out = acc;
}

// ---------------------------------------------------------------------------
// K2: gate combine + GEMM2 + wave-parallel top-3 + sigmoid.
// ---------------------------------------------------------------------------
__global__ __launch_bounds__(128) void k_gate2(const float* __restrict__ hpart,
                                               const float* __restrict__ gb1,
                                               const float* __restrict__ gw2,
                                               const float* __restrict__ gb2,
                                               float* __restrict__ out_gw,
                                               int* __restrict__ sel_idx,
                                               float* __restrict__ sel_w) {
  int b = blockIdx.x;
  int t = threadIdx.x;

  __shared__ float hid[GH_];
  __shared__ float logitS[P_];
  __shared__ int   s_idx[K_];
  __shared__ float s_val[K_];

  float s = gb1[t];
  for (int kc = 0; kc < 8; ++kc)
    s += hpart[((size_t)kc * B_ + b) * GH_ + t];
  hid[t] = fmaxf(s, 0.f);
  __syncthreads();

  float acc = gb2[t];
  for (int jj = 0; jj < GH_; ++jj)
    acc = fmaf(hid[jj], gw2[(size_t)jj * P_ + t], acc);
  logitS[t] = acc;
  __syncthreads();

  if (t < 64) {
    float v0 = logitS[t], v1 = logitS[t + 64];
    int i0 = t, i1 = t + 64;
    for (int k = 0; k < K_; ++k) {
      float v; int i;
      if (v0 > v1 || (v0 == v1 && i0 < i1)) { v = v0; i = i0; }
      else                                  { v = v1; i = i1; }
      for (int sft = 1; sft < 64; sft <<= 1) {
        float ov = __shfl_xor(v, sft);
        int   oi = __shfl_xor(i, sft);
        if (ov > v || (ov == v && oi < i)) { v = ov; i = oi; }
      }
      if (t == 0) {
        float w = 1.f / (1.f + expf(-v));
        s_idx[k] = i; s_val[k] = w;
        sel_idx[b * K_ + k] = i;
        sel_w[b * K_ + k] = w;
      }
      if (i0 == i) v0 = -INFINITY;
      if (i1 == i) v1 = -INFINITY;
    }
  }
  __syncthreads();

  float gwv = 0.f;
  for (int k = 0; k < K_; ++k) if (s_idx[k] == t) gwv = s_val[k];
  out_gw[(size_t)b * P_ + t] = gwv;
}

// ---------------------------------------------------------------------------
// K3: parallel stable rank-sort by pathway + inverse perm + pathway offsets.
//   blocks 0..11: sorted_bk / inv for 64 slots each; block 12: pstart[0..128].
// ---------------------------------------------------------------------------
__global__ __launch_bounds__(64) void k_sort2(const int* __restrict__ sel_idx,
                                              int* __restrict__ sorted_bk,
                                              int* __restrict__ inv,
                                              int* __restrict__ pstart) {
  __shared__ int pk[B_ * K_];
  int t = threadIdx.x;
  for (int i = t; i < B_ * K_; i += 64) pk[i] = sel_idx[i];
  __syncthreads();
  if (blockIdx.x < 12) {
    int slot = blockIdx.x * 64 + t;
    int mine = pk[slot];
    int rank = 0;
    for (int i = 0; i < B_ * K_; ++i) {
      int pi = pk[i];
      rank += (pi < mine) || (pi == mine && i < slot);
    }
    sorted_bk[rank] = slot;
    inv[slot] = rank;
  } else {
    for (int pp = t; pp <= P_; pp += 64) {
      int cp = 0;
      for (int i = 0; i < B_ * K_; ++i) cp += (pk[i] < pp);
      pstart[pp] = cp;
    }
  }
}

// ---------------------------------------------------------------------------
// K4: pathway-grouped expert. Block = (pathway p, gene-chunk c). Reads each
// active W1 row ONCE and applies it to all samples that selected p (groups
// of 32: 4 waves x 8 reg-accumulators). Writes chunk partials
// hpart2[slot][c][h] (slot = position in pathway-sorted order).
// ---------------------------------------------------------------------------
__global__ __launch_bounds__(256) void k_expert_p(const float* __restrict__ xr,
                                                  const float* __restrict__ xc,
                                                  const float* __restrict__ xm,
                                                  const float* __restrict__ W1,
                                                  const int* __restrict__ cnt,
                                                  const int* __restrict__ list,
                                                  const int* __restrict__ sorted_bk,
                                                  const int* __restrict__ pstart,
                                                  float* __restrict__ hpart2) {
  int p = blockIdx.x >> 3;
  int c = blockIdx.x & 7;
  int t = threadIdx.x;
  int h = t & 63;
  int w = t >> 6;                 // 0..3
  int s0 = pstart[p], s1 = pstart[p + 1];
  int S = s1 - s0;
  if (S == 0) return;
  int n = cnt[p];
  int gch = (n + NCHK_ - 1) / NCHK_;
  int c0 = c * gch; if (c0 > n) c0 = n;
  int c1 = c0 + gch; if (c1 > n) c1 = n;
  const int* lp = list + (size_t)p * G_;
  const float* W1p = W1 + (size_t)p * D_ * H_;

  __shared__ int   glist[GT_];
  __shared__ int   bs[SG_];
  __shared__ float xv[3][SG_][GT_];   // 24 KB

  for (int sg0 = 0; sg0 < S; sg0 += SG_) {
    int Sg = S - sg0; if (Sg > SG_) Sg = SG_;
    __syncthreads();
    if (t < Sg) bs[t] = sorted_bk[s0 + sg0 + t] / K_;
    float acc[8];
#pragma unroll
    for (int j = 0; j < 8; ++j) acc[j] = 0.f;

    for (int gb = c0; gb < c1; gb += GT_) {
      int gn = c1 - gb; if (gn > GT_) gn = GT_;
      __syncthreads();
      if (t < gn) glist[t] = lp[gb + t];
      __syncthreads();
      // stage xv[omic][s][i] (pow2 index math; invalid region untouched/unused)
      for (int idx = t; idx < 3 * SG_ * GT_; idx += 256) {
        int i = idx & (GT_ - 1);
        int srow = idx >> 6;
        int s = srow & (SG_ - 1);
        int omic = srow >> 5;
        if (s < Sg && i < gn) {
          int g = glist[i];
          const float* xp = (omic == 0) ? xr : (omic == 1) ? xc : xm;
          xv[omic][s][i] = xp[(size_t)bs[s] * G_ + g];
        }
      }
      __syncthreads();
      for (int i = 0; i < gn; ++i) {
        int g = glist[i];
        const float* r = W1p + (size_t)g * H_ + h;
        float r0 = r[0];
        float r1 = r[(size_t)G_ * H_];
        float r2 = r[(size_t)(2 * G_) * H_];
#pragma unroll
        for (int j = 0; j < 8; ++j) {
          int s = j * 4 + w;
          if (s >= Sg) break;     // wave-uniform
          acc[j] = fmaf(xv[0][s][i], r0, acc[j]);
          acc[j] = fmaf(xv[1][s][i], r1, acc[j]);
          acc[j] = fmaf(xv[2][s][i], r2, acc[j]);
        }
      }
    }
#pragma unroll
    for (int j = 0; j < 8; ++j) {
      int s = j * 4 + w;
      if (s >= Sg) break;
      hpart2[((size_t)(s0 + sg0 + s) * NCHK_ + c) * H_ + h] = acc[j];
    }
  }
}

// ---------------------------------------------------------------------------
// K5: fused combine: sum chunk partials + BN + ReLU + W2 + gate-weighted sum
// + classifier. One block (192 thr = 3 waves, wave per k) per sample.
// ---------------------------------------------------------------------------
__global__ __launch_bounds__(192) void k_final2(const float* __restrict__ hpart2,
                                                const int* __restrict__ inv,
                                                const int* __restrict__ sel_idx,
                                                const float* __restrict__ sel_w,
                                                const float* __restrict__ b1,
                                                const float* __restrict__ bn_g,
                                                const float* __restrict__ bn_b,
                                                const float* __restrict__ bn_m,
                                                const float* __restrict__ bn_v,
                                                const float* __restrict__ W2,
                                                const float* __restrict__ b2,
                                                const float* __restrict__ cw1,
                                                const float* __restrict__ cb1,
                                                const float* __restrict__ cw2,
                                                const float* __restrict__ cb2,
                                                float* __restrict__ out_logits) {
  int b = blockIdx.x;
  int t = threadIdx.x;
  int k = t >> 6;
  int h = t & 63;

  __shared__ float hs[K_][H_];
  __shared__ float eoS[K_][O_];
  __shared__ float fs[O_];
  __shared__ float chS[CH_];
  __shared__ int   pS[K_];
  __shared__ float wS[K_];

  int bk = b * K_ + k;
  int slot = inv[bk];
  int p = sel_idx[bk];
  if (h == 0) { pS[k] = p; wS[k] = sel_w[bk]; }

  float s = 0.f;
#pragma unroll
  for (int cc = 0; cc < NCHK_; ++cc)
    s += hpart2[((size_t)slot * NCHK_ + cc) * H_ + h];
  int ph = p * H_ + h;
  s += b1[ph];
  float hn = (s - bn_m[ph]) * (bn_g[ph] * rsqrtf(bn_v[ph] + EPS_)) + bn_b[ph];
  hs[k][h] = fmaxf(hn, 0.f);
  __syncthreads();

  if (t < K_ * O_) {               // 48 threads
    int k2 = t >> 4;
    int o = t & 15;
    int p2 = pS[k2];
    const float* W2p = W2 + (size_t)p2 * H_ * O_;
    float e = b2[p2 * O_ + o];
    for (int jj = 0; jj < H_; ++jj) e = fmaf(hs[k2][jj], W2p[jj * O_ + o], e);
    eoS[k2][o] = e;
  }
  __syncthreads();

  if (t < O_) {
    float f = 0.f;
    for (int kk = 0; kk < K_; ++kk) f += wS[kk] * eoS[kk][t];
    fs[t] = f;
  }
  __syncthreads();

  if (t < CH_) {
    float a = cb1[t];
    for (int o = 0; o < O_; ++o) a = fmaf(fs[o], cw1[o * CH_ + t], a);
    chS[t] = fmaxf(a, 0.f);
  }
  __syncthreads();

  if (t < C_) {
    float a = cb2[t];
    for (int jj = 0; jj < CH_; ++jj) a = fmaf(chS[jj], cw2[jj * C_ + t], a);
    out_logits[(size_t)b * C_ + t] = a;
  }
}

// ---------------------------------------------------------------------------
extern "C" void kernel_launch(void* const* d_in, const int* in_sizes, int n_in,
                              void* d_out, int out_size, void* d_ws, size_t ws_size,
                              hipStream_t stream) {
  const float* x_rna    = (const float*)d_in[0];
  const float* x_cnv    = (const float*)d_in[1];
  const float* x_met    = (const float*)d_in[2];
  const float* gene_mask= (const float*)d_in[3];
  const float* gate_w1  = (const float*)d_in[4];
  const float* gate_b1  = (const float*)d_in[5];
  const float* gate_w2  = (const float*)d_in[6];
  const float* gate_b2  = (const float*)d_in[7];
  const float* W1       = (const float*)d_in[8];
  const float* b1       = (const float*)d_in[9];
  const float* bn_g     = (const float*)d_in[10];
  const float* bn_b     = (const float*)d_in[11];
  const float* bn_m     = (const float*)d_in[12];
  const float* bn_v     = (const float*)d_in[13];
  const float* W2       = (const float*)d_in[14];
  const float* b2       = (const float*)d_in[15];
  const float* cls_w1   = (const float*)d_in[16];
  const float* cls_b1   = (const float*)d_in[17];
  const float* cls_w2   = (const float*)d_in[18];
  const float* cls_b2   = (const float*)d_in[19];

  float* out_logits = (float*)d_out;                   // [B, C]
  float* out_gw     = (float*)d_out + (size_t)B_ * C_; // [B, P]

  // workspace layout (bytes)
  char* ws = (char*)d_ws;
  int*   cnt     = (int*)(ws + 0);                 // 512
  int*   list    = (int*)(ws + 512);               // 2,048,000
  int*   sel_idx = (int*)(ws + 2048512);           // 3072
  float* sel_w   = (float*)(ws + 2051584);         // 3072
  int*   sorted  = (int*)(ws + 2054656);           // 3072
  int*   inv     = (int*)(ws + 2057728);           // 3072
  int*   pstart  = (int*)(ws + 2060800);           // 1024 (129 used)
  float* hpart   = (float*)(ws + 2061824);         // 1,048,576
  float* hpart2  = (float*)(ws + 3110400);         // 1,572,864

  hipLaunchKernelGGL(k_pre, dim3(P_ + 256), dim3(512), 0, stream,
                     gene_mask, x_rna, gate_w1, cnt, list, hpart);
  hipLaunchKernelGGL(k_gate2, dim3(B_), dim3(128), 0, stream,
                     hpart, gate_b1, gate_w2, gate_b2, out_gw, sel_idx, sel_w);
  hipLaunchKernelGGL(k_sort2, dim3(13), dim3(64), 0, stream,
                     sel_idx, sorted, inv, pstart);
  hipLaunchKernelGGL(k_expert_p, dim3(P_ * NCHK_), dim3(256), 0, stream,
                     x_rna, x_cnv, x_met, W1, cnt, list, sorted, pstart, hpart2);
  hipLaunchKernelGGL(k_final2, dim3(B_), dim3(192), 0, stream,
                     hpart2, inv, sel_idx, sel_w, b1, bn_g, bn_b, bn_m, bn_v,
                     W2, b2, cls_w1, cls_b1, cls_w2, cls_b2, out_logits);
}

// Round 5
// 67.658 us; speedup vs baseline: 3.2196x; 3.2196x over previous
//
#include <hip/hip_runtime.h>
#include <math.h>

#define B_ 256
#define G_ 4000
#define P_ 128
#define D_ 12000
#define H_ 64
#define O_ 16
#define GH_ 128
#define CH_ 8
#define C_ 5
#define K_ 3
#define EPS_ 1e-5f
#define TILE_ 1024
#define KCH_ 500   // K-chunk per gemm1 block (4000/8)
#define KIN_ 100   // inner K tile staged in LDS

// ---------------------------------------------------------------------------
// K1: fused preprocessing.
//   blocks [0,128):    per-pathway active-gene compaction (8 waves, 2-pass)
//   blocks [128,384):  gate GEMM1 partials over 8 k-chunks
// ---------------------------------------------------------------------------
__global__ __launch_bounds__(512) void k_pre(const float* __restrict__ gene_mask,
                                             const float* __restrict__ x_rna,
                                             const float* __restrict__ gw1,
                                             int* __restrict__ cnt,
                                             int* __restrict__ list,
                                             float* __restrict__ hpart) {
  int t = threadIdx.x;

  if (blockIdx.x < P_) {
    int p = blockIdx.x;
    int lane = t & 63;
    int w = t >> 6;
    __shared__ int wcnt[8];
    int* lp = list + (size_t)p * G_;
    const int per = (G_ + 7) / 8;   // 500
    int start = w * per;
    int end = start + per; if (end > G_) end = G_;

    int count = 0;
    for (int g0 = start; g0 < end; g0 += 64) {
      int g = g0 + lane;
      bool act = (g < end) && (gene_mask[(size_t)g * P_ + p] != 0.0f);
      count += __popcll(__ballot(act));
    }
    if (lane == 0) wcnt[w] = count;
    __syncthreads();
    if (t == 0) {
      int tot = 0;
      for (int i = 0; i < 8; ++i) tot += wcnt[i];
      cnt[p] = tot;
    }
    int base = 0;
    for (int i = 0; i < w; ++i) base += wcnt[i];
    for (int g0 = start; g0 < end; g0 += 64) {
      int g = g0 + lane;
      bool act = (g < end) && (gene_mask[(size_t)g * P_ + p] != 0.0f);
      unsigned long long bal = __ballot(act);
      int rank = __popcll(bal & ((1ull << lane) - 1ull));
      if (act) lp[base + rank] = g;
      base += __popcll(bal);
    }
    return;
  }

  // ---- gate GEMM1 partial tile ----
  int idx = blockIdx.x - P_;        // 0..255
  int bt = idx >> 5;                // 8 b-tiles of 32
  int sub = idx & 31;
  int jt = sub >> 3;                // 4 j-tiles of 32
  int kc = sub & 7;                 // 8 k-chunks of 500
  int b0 = bt * 32;
  int j0 = jt * 32;

  __shared__ float xa[32 * KIN_];
  __shared__ float wa[KIN_ * 32];
  float2* wa2 = (float2*)wa;

  int bi = t >> 4;
  int jp = t & 15;
  float2 acc = {0.f, 0.f};

  for (int ch = 0; ch < KCH_ / KIN_; ++ch) {
    int kb = kc * KCH_ + ch * KIN_;
    __syncthreads();
    for (int id = t; id < 32 * KIN_; id += 512) {
      int r = id / KIN_, c = id - r * KIN_;
      xa[id] = x_rna[(size_t)(b0 + r) * G_ + kb + c];
    }
    for (int id = t; id < KIN_ * 32; id += 512) {
      int r = id >> 5, c = id & 31;
      wa[id] = gw1[(size_t)(kb + r) * GH_ + j0 + c];
    }
    __syncthreads();
#pragma unroll 4
    for (int kk = 0; kk < KIN_; ++kk) {
      float a = xa[bi * KIN_ + kk];
      float2 w = wa2[kk * 16 + jp];
      acc.x = fmaf(a, w.x, acc.x);
      acc.y = fmaf(a, w.y, acc.y);
    }
  }
  float2* out = (float2*)(hpart + ((size_t)kc * B_ + (b0 + bi)) * GH_ + j0 + jp * 2);
  *out = acc;
}

// ---------------------------------------------------------------------------
// K2: gate combine + GEMM2 + wave-parallel top-3 + sigmoid.
// ---------------------------------------------------------------------------
__global__ __launch_bounds__(128) void k_gate2(const float* __restrict__ hpart,
                                               const float* __restrict__ gb1,
                                               const float* __restrict__ gw2,
                                               const float* __restrict__ gb2,
                                               float* __restrict__ out_gw,
                                               int* __restrict__ sel_idx,
                                               float* __restrict__ sel_w) {
  int b = blockIdx.x;
  int t = threadIdx.x;

  __shared__ float hid[GH_];
  __shared__ float logitS[P_];
  __shared__ int   s_idx[K_];
  __shared__ float s_val[K_];

  float s = gb1[t];
  for (int kc = 0; kc < 8; ++kc)
    s += hpart[((size_t)kc * B_ + b) * GH_ + t];
  hid[t] = fmaxf(s, 0.f);
  __syncthreads();

  float acc = gb2[t];
  for (int jj = 0; jj < GH_; ++jj)
    acc = fmaf(hid[jj], gw2[(size_t)jj * P_ + t], acc);
  logitS[t] = acc;
  __syncthreads();

  if (t < 64) {
    float v0 = logitS[t], v1 = logitS[t + 64];
    int i0 = t, i1 = t + 64;
    for (int k = 0; k < K_; ++k) {
      float v; int i;
      if (v0 > v1 || (v0 == v1 && i0 < i1)) { v = v0; i = i0; }
      else                                  { v = v1; i = i1; }
      for (int sft = 1; sft < 64; sft <<= 1) {
        float ov = __shfl_xor(v, sft);
        int   oi = __shfl_xor(i, sft);
        if (ov > v || (ov == v && oi < i)) { v = ov; i = oi; }
      }
      if (t == 0) {
        float w = 1.f / (1.f + expf(-v));
        s_idx[k] = i; s_val[k] = w;
        sel_idx[b * K_ + k] = i;
        sel_w[b * K_ + k] = w;
      }
      if (i0 == i) v0 = -INFINITY;
      if (i1 == i) v1 = -INFINITY;
    }
  }
  __syncthreads();

  float gwv = 0.f;
  for (int k = 0; k < K_; ++k) if (s_idx[k] == t) gwv = s_val[k];
  out_gw[(size_t)b * P_ + t] = gwv;
}

// ---------------------------------------------------------------------------
// K3: expert compute, one block (8 waves) per (sample, pathway) selection.
// x values staged in LDS (round-2 structure). W1 read via float4 gathers:
// lane = 16*(gene subgroup j) + h-quad hq; one wave instruction covers
// 4 genes x 1KB instead of 1 gene x 256B (4x fewer gather instructions).
// Per-wave partials to LDS part[32][64], reduced by 64 threads, then
// BN + ReLU + W2 -> eo[bk].
// ---------------------------------------------------------------------------
__global__ __launch_bounds__(512) void k_expert(const float* __restrict__ xr,
                                                const float* __restrict__ xc,
                                                const float* __restrict__ xm,
                                                const float* __restrict__ W1,
                                                const float* __restrict__ b1,
                                                const float* __restrict__ bn_g,
                                                const float* __restrict__ bn_b,
                                                const float* __restrict__ bn_m,
                                                const float* __restrict__ bn_v,
                                                const float* __restrict__ W2,
                                                const float* __restrict__ b2,
                                                const int* __restrict__ cnt,
                                                const int* __restrict__ list,
                                                const int* __restrict__ sel_idx,
                                                float* __restrict__ eo) {
  int bk = blockIdx.x;              // 768 blocks
  int b = bk / K_;
  int t = threadIdx.x;
  int w = t >> 6;                   // wave 0..7
  int lane = t & 63;
  int j = lane >> 4;                // gene subgroup 0..3
  int hq = lane & 15;               // h-quad: h = hq*4..hq*4+3
  int p = sel_idx[bk];
  int n = cnt[p];
  const int* lp = list + (size_t)p * G_;
  const float* W1p = W1 + (size_t)p * D_ * H_;
  const float* xrb = xr + (size_t)b * G_;
  const float* xcb = xc + (size_t)b * G_;
  const float* xmb = xm + (size_t)b * G_;

  __shared__ int   glist[TILE_];
  __shared__ float xv0[TILE_], xv1[TILE_], xv2[TILE_];
  __shared__ float part[32][H_];    // 8 KB
  __shared__ float hs[H_];

  float a0 = 0.f, a1 = 0.f, a2 = 0.f, a3 = 0.f;

  for (int t0 = 0; t0 < n; t0 += TILE_) {
    int m = n - t0; if (m > TILE_) m = TILE_;
    __syncthreads();
    for (int i = t; i < m; i += 512) {
      int g = lp[t0 + i];
      glist[i] = g;
      xv0[i] = xrb[g]; xv1[i] = xcb[g]; xv2[i] = xmb[g];
    }
    __syncthreads();
    // wave w handles genes w*4+j + 32*it
    for (int i0 = w * 4 + j; i0 < m; i0 += 32) {
      // (i0 always < m for active lanes; subgroup granularity handled by +=32
      //  with per-lane i0 -- lanes with i0 >= m simply skip)
      int g = glist[i0];
      float x0 = xv0[i0], x1 = xv1[i0], x2 = xv2[i0];
      const float* r = W1p + (size_t)g * H_ + hq * 4;
      float4 w0 = *(const float4*)r;
      float4 w1 = *(const float4*)(r + (size_t)G_ * H_);
      float4 w2 = *(const float4*)(r + (size_t)(2 * G_) * H_);
      a0 = fmaf(x0, w0.x, a0); a1 = fmaf(x0, w0.y, a1);
      a2 = fmaf(x0, w0.z, a2); a3 = fmaf(x0, w0.w, a3);
      a0 = fmaf(x1, w1.x, a0); a1 = fmaf(x1, w1.y, a1);
      a2 = fmaf(x1, w1.z, a2); a3 = fmaf(x1, w1.w, a3);
      a0 = fmaf(x2, w2.x, a0); a1 = fmaf(x2, w2.y, a1);
      a2 = fmaf(x2, w2.z, a2); a3 = fmaf(x2, w2.w, a3);
    }
  }
  {
    float4 av = {a0, a1, a2, a3};
    *(float4*)&part[w * 4 + j][hq * 4] = av;
  }
  __syncthreads();

  if (t < H_) {
    float s = 0.f;
#pragma unroll
    for (int ss = 0; ss < 32; ++ss) s += part[ss][t];
    int ph = p * H_ + t;
    s += b1[ph];
    float hn = (s - bn_m[ph]) * (bn_g[ph] * rsqrtf(bn_v[ph] + EPS_)) + bn_b[ph];
    hs[t] = fmaxf(hn, 0.f);
  }
  __syncthreads();

  if (t < O_) {
    const float* W2p = W2 + (size_t)p * H_ * O_;
    float o = b2[p * O_ + t];
    for (int jj = 0; jj < H_; ++jj) o = fmaf(hs[jj], W2p[jj * O_ + t], o);
    eo[(size_t)bk * O_ + t] = o;
  }
}

// ---------------------------------------------------------------------------
// K4: weighted combine of the K expert outputs + classifier MLP.
// ---------------------------------------------------------------------------
__global__ __launch_bounds__(64) void k_final(const float* __restrict__ eo,
                                              const float* __restrict__ sel_w,
                                              const float* __restrict__ cw1,
                                              const float* __restrict__ cb1,
                                              const float* __restrict__ cw2,
                                              const float* __restrict__ cb2,
                                              float* __restrict__ out_logits) {
  int b = blockIdx.x * blockDim.x + threadIdx.x;
  if (b >= B_) return;
  float feat[O_];
  float w0 = sel_w[b * K_ + 0], w1 = sel_w[b * K_ + 1], w2 = sel_w[b * K_ + 2];
  const float* e0 = eo + (size_t)(b * K_ + 0) * O_;
  const float* e1 = eo + (size_t)(b * K_ + 1) * O_;
  const float* e2 = eo + (size_t)(b * K_ + 2) * O_;
  for (int o = 0; o < O_; ++o)
    feat[o] = w0 * e0[o] + w1 * e1[o] + w2 * e2[o];

  float ch[CH_];
  for (int jj = 0; jj < CH_; ++jj) {
    float a = cb1[jj];
    for (int o = 0; o < O_; ++o) a = fmaf(feat[o], cw1[o * CH_ + jj], a);
    ch[jj] = fmaxf(a, 0.f);
  }
  for (int c = 0; c < C_; ++c) {
    float a = cb2[c];
    for (int jj = 0; jj < CH_; ++jj) a = fmaf(ch[jj], cw2[jj * C_ + c], a);
    out_logits[(size_t)b * C_ + c] = a;
  }
}

// ---------------------------------------------------------------------------
extern "C" void kernel_launch(void* const* d_in, const int* in_sizes, int n_in,
                              void* d_out, int out_size, void* d_ws, size_t ws_size,
                              hipStream_t stream) {
  const float* x_rna    = (const float*)d_in[0];
  const float* x_cnv    = (const float*)d_in[1];
  const float* x_met    = (const float*)d_in[2];
  const float* gene_mask= (const float*)d_in[3];
  const float* gate_w1  = (const float*)d_in[4];
  const float* gate_b1  = (const float*)d_in[5];
  const float* gate_w2  = (const float*)d_in[6];
  const float* gate_b2  = (const float*)d_in[7];
  const float* W1       = (const float*)d_in[8];
  const float* b1       = (const float*)d_in[9];
  const float* bn_g     = (const float*)d_in[10];
  const float* bn_b     = (const float*)d_in[11];
  const float* bn_m     = (const float*)d_in[12];
  const float* bn_v     = (const float*)d_in[13];
  const float* W2       = (const float*)d_in[14];
  const float* b2       = (const float*)d_in[15];
  const float* cls_w1   = (const float*)d_in[16];
  const float* cls_b1   = (const float*)d_in[17];
  const float* cls_w2   = (const float*)d_in[18];
  const float* cls_b2   = (const float*)d_in[19];

  float* out_logits = (float*)d_out;                   // [B, C]
  float* out_gw     = (float*)d_out + (size_t)B_ * C_; // [B, P]

  // workspace layout (bytes)
  char* ws = (char*)d_ws;
  int*   cnt     = (int*)(ws + 0);                 // 512
  int*   list    = (int*)(ws + 512);               // 2,048,000
  int*   sel_idx = (int*)(ws + 2048512);           // 3072
  float* sel_w   = (float*)(ws + 2051584);         // 3072
  float* eo      = (float*)(ws + 2054656);         // 49152
  float* hpart   = (float*)(ws + 2103808);         // 1,048,576

  hipLaunchKernelGGL(k_pre, dim3(P_ + 256), dim3(512), 0, stream,
                     gene_mask, x_rna, gate_w1, cnt, list, hpart);
  hipLaunchKernelGGL(k_gate2, dim3(B_), dim3(128), 0, stream,
                     hpart, gate_b1, gate_w2, gate_b2, out_gw, sel_idx, sel_w);
  hipLaunchKernelGGL(k_expert, dim3(B_ * K_), dim3(512), 0, stream,
                     x_rna, x_cnv, x_met, W1, b1, bn_g, bn_b, bn_m, bn_v,
                     W2, b2, cnt, list, sel_idx, eo);
  hipLaunchKernelGGL(k_final, dim3((B_ + 63) / 64), dim3(64), 0, stream,
                     eo, sel_w, cls_w1, cls_b1, cls_w2, cls_b2, out_logits);
}